// Round 5
// baseline (272.887 us; speedup 1.0000x reference)
//
#include <hip/hip_runtime.h>
#include <stdint.h>

#define N_TOKENS 32768
#define N_CODES  8192
#define DIM      256
#define EPSF     1e-8f

typedef __bf16 bf16x8 __attribute__((ext_vector_type(8)));
typedef float  f32x4  __attribute__((ext_vector_type(4)));

// ws layout: [bf16 codebooks 4MiB][cnorm f32 32KiB][hist i32 32KiB]
#define WS_CNORM_OFF  (4u*1024u*1024u)
#define WS_HIST_OFF   (WS_CNORM_OFF + N_CODES*4u)

__device__ int g_ctr;   // k_argmin block-completion counter (zeroed by k_prep)

// ---------------------------------------------------------------------------
// K1: codebooks fp32 -> bf16, ||c||^2, zero histogram + completion counter.
// ---------------------------------------------------------------------------
__global__ __launch_bounds__(256) void k_prep(const float* __restrict__ cbf,
                                              unsigned short* __restrict__ cbh,
                                              float* __restrict__ cnorm,
                                              int* __restrict__ hist) {
    const int tid = blockIdx.x * 256 + threadIdx.x;
    if (tid < N_CODES) hist[tid] = 0;
    if (tid == 0) g_ctr = 0;

    const int w = threadIdx.x >> 6;
    const int lane = threadIdx.x & 63;
    const int row = blockIdx.x * 4 + w;

    const float4 v = ((const float4*)(cbf + (size_t)row * DIM))[lane];
    float sq = v.x * v.x + v.y * v.y + v.z * v.z + v.w * v.w;

    ushort4 u;
    u.x = __builtin_bit_cast(unsigned short, (__bf16)v.x);
    u.y = __builtin_bit_cast(unsigned short, (__bf16)v.y);
    u.z = __builtin_bit_cast(unsigned short, (__bf16)v.z);
    u.w = __builtin_bit_cast(unsigned short, (__bf16)v.w);
    ((ushort4*)(cbh + (size_t)row * DIM))[lane] = u;

    #pragma unroll
    for (int d = 1; d < 64; d <<= 1) sq += __shfl_xor(sq, d);
    if (lane == 0) cnorm[row] = sq;
}

// ---------------------------------------------------------------------------
// K2: fused distance-matmul + argmax(x.c - cn/2) + quant + stats, v10.
//  v10 vs v9: fix the IN-ORDER-vmcnt drain. v9's per-chunk cnorm load was
//  the NEWEST vmem op, so waiting for it at the tail forced vmcnt(0) ->
//  drained the 8 stage-DMAs issued only ~1/2 chunk earlier -> every chunk
//  ate the contended L2 round trip. All of v5b/v6/v8/v9 shared this
//  one-full-drain-per-chunk structure (all ~165-180us, MfmaUtil ~34%).
//  Now: cn is loaded via inline asm at chunk TOP, BEFORE the stage DMAs,
//  making it the OLDEST outstanding op; the tail waits `s_waitcnt vmcnt(8)`
//  (retires cn, keeps all 8 DMAs in flight). The only vmcnt(0) is the
//  chunk-top wait on stage(cc), issued a FULL chunk earlier (~free).
//  The cn dependency is threaded with "+v"(cn) so the consumer can't be
//  hoisted above the wait (rule #18). Loop remains barrier-free with
//  per-wave private double-buffered staging (16 codes/wave, dbuf 8KB).
//  k_stats merged here: last block (completion counter) computes stats.
// ---------------------------------------------------------------------------
__global__ __launch_bounds__(512, 2) void k_argmin(const float* __restrict__ X,
                                                   const float* __restrict__ R,
                                                   const unsigned short* __restrict__ cbh,
                                                   const float* __restrict__ cnorm,
                                                   float* __restrict__ out,
                                                   int* __restrict__ hist) {
    // layout: [0,131072) wave-private B bufs: wave w at w*16384, dbuf +0/+8192
    //         [131072,133120) redv[8][64] | [133120,135168) redi[8][64]
    //         [135168,135680) maxvS[128]
    // A-stage (128 tok x 544B = 69632B) transiently overlays [0,69632).
    __shared__ __attribute__((aligned(16))) char smem[135680];
    __shared__ int amLast;
    float* redv  = (float*)(smem + 131072);
    int*   redi  = (int*)(smem + 133120);
    float* maxvS = (float*)(smem + 135168);

    const int tid  = threadIdx.x;
    const int w    = tid >> 6;
    const int lane = tid & 63;
    const int lr   = lane & 15;
    const int lq   = lane >> 4;
    const int th   = w >> 2;          // token half
    const int wc   = w & 3;           // code quarter
    const int r0   = blockIdx.x * 128;
    const int mycol = wc * 16 + lr;

    // ---- A-stage: wave w loads tokens [16w,16w+16), row stride 544B ----
    {
        const float4* Xf4 = (const float4*)(X + (size_t)(r0 + 16 * w) * DIM);
        #pragma unroll
        for (int i = 0; i < 16; ++i) {
            const float4 v = Xf4[i * 64 + lane];
            ushort4 u;
            u.x = __builtin_bit_cast(unsigned short, (__bf16)v.x);
            u.y = __builtin_bit_cast(unsigned short, (__bf16)v.y);
            u.z = __builtin_bit_cast(unsigned short, (__bf16)v.z);
            u.w = __builtin_bit_cast(unsigned short, (__bf16)v.w);
            *(ushort4*)(smem + (16 * w + i) * 544 + lane * 8) = u;
        }
    }
    __syncthreads();

    bf16x8 A[4][8];
    #pragma unroll
    for (int mf = 0; mf < 4; ++mf)
        #pragma unroll
        for (int kc = 0; kc < 8; ++kc)
            A[mf][kc] = *(const bf16x8*)(smem + (64 * th + mf * 16 + lr) * 544 + kc * 64 + lq * 16);
    __syncthreads();   // ALL waves' A reads done before any private staging lands

    // ---- private staging: wave w stages codes [16wc,16wc+16), 8 DMAs/chunk.
    //  DMA d covers local rows 2d,2d+1 (1KB). Source slot swizzle j=(l5-c)&31
    //  pairs with read slot s=(kc*4+lq+mycol)&31. HW dest = base+lane*16 ✓.
    const int half = lane >> 5, l5 = lane & 31;
    int srcoff[8];
    #pragma unroll
    for (int d = 0; d < 8; ++d) {
        const int c = 16 * wc + 2 * d + half;
        const int j = (l5 - c) & 31;
        srcoff[d] = c * 512 + j * 16;
    }
    const char* cbb = (const char*)cbh;
    char* mybase = smem + w * 16384;

    // ---- stage chunk 0 into private buf 0 ----
    #pragma unroll
    for (int d = 0; d < 8; ++d)
        __builtin_amdgcn_global_load_lds(
            (const __attribute__((address_space(1))) unsigned int*)(cbb + srcoff[d]),
            (__attribute__((address_space(3))) unsigned int*)(mybase + d * 1024),
            16, 0, 0);

    float maxv[16];
    int   maxi[16];
    #pragma unroll
    for (int i = 0; i < 16; ++i) { maxv[i] = -3.4e38f; maxi[i] = 0; }

    for (int cc = 0; cc < 128; ++cc) {
        const int cur = (cc & 1) * 8192;

        // wait only for OWN stage(cc), issued a full chunk ago -> ~free.
        asm volatile("s_waitcnt vmcnt(0)" ::: "memory");

        // cn load FIRST (oldest outstanding vmem of this iteration) so the
        // tail can retire it with vmcnt(8) without draining the stage DMAs.
        float cn;
        asm volatile("global_load_dword %0, %1, off"
                     : "=v"(cn)
                     : "v"(cnorm + cc * 64 + mycol));

        // issue stage(cc+1) into the other private buffer (stays in flight
        // across the whole chunk; retired at next chunk top).
        if (cc + 1 < 128) {
            const char* src = cbb + (size_t)(cc + 1) * 32768;
            const int nxt = ((cc + 1) & 1) * 8192;
            #pragma unroll
            for (int d = 0; d < 8; ++d)
                __builtin_amdgcn_global_load_lds(
                    (const __attribute__((address_space(1))) unsigned int*)(src + srcoff[d]),
                    (__attribute__((address_space(3))) unsigned int*)(mybase + nxt + d * 1024),
                    16, 0, 0);
        }

        bf16x8 b[8];
        #pragma unroll
        for (int kc = 0; kc < 8; ++kc)
            b[kc] = *(const bf16x8*)(mybase + cur + lr * 512 +
                                     (((kc * 4 + lq + mycol) & 31) << 4));

        f32x4 acc[4];
        #pragma unroll
        for (int mf = 0; mf < 4; ++mf) {
            acc[mf][0] = 0.f; acc[mf][1] = 0.f; acc[mf][2] = 0.f; acc[mf][3] = 0.f;
        }

        #pragma unroll
        for (int kc = 0; kc < 8; ++kc)
            #pragma unroll
            for (int mf = 0; mf < 4; ++mf)
                acc[mf] = __builtin_amdgcn_mfma_f32_16x16x32_bf16(A[mf][kc], b[kc], acc[mf], 0, 0, 0);

        // retire ONLY cn (oldest); stage(cc+1)'s 8 DMAs stay outstanding.
        if (cc + 1 < 128) {
            asm volatile("s_waitcnt vmcnt(8)" : "+v"(cn));
        } else {
            asm volatile("s_waitcnt vmcnt(0)" : "+v"(cn));
        }

        const int col = cc * 64 + mycol;
        #pragma unroll
        for (int mf = 0; mf < 4; ++mf)
            #pragma unroll
            for (int r = 0; r < 4; ++r) {
                const float v = fmaf(-0.5f, cn, acc[mf][r]);
                const int j = mf * 4 + r;
                if (v > maxv[j]) { maxv[j] = v; maxi[j] = col; }
            }
    }

    // ---- reduce across the 16 lanes (lr) sharing each token row ----
    #pragma unroll
    for (int mf = 0; mf < 4; ++mf)
        #pragma unroll
        for (int r = 0; r < 4; ++r) {
            float v = maxv[mf * 4 + r]; int ix = maxi[mf * 4 + r];
            #pragma unroll
            for (int d = 1; d <= 8; d <<= 1) {
                const float ov = __shfl_xor(v, d);
                const int   oi = __shfl_xor(ix, d);
                if (ov > v || (ov == v && oi < ix)) { v = ov; ix = oi; }
            }
            if (lr == 0) {
                const int row = mf * 16 + lq * 4 + r;   // token row within half
                redv[w * 64 + row] = v; redi[w * 64 + row] = ix;
            }
        }
    __syncthreads();

    // ---- combine the 4 code-quarter waves per token; hist + maxvS ----
    if (tid < 128) {
        const int t = tid, tth = t >> 6, tl = t & 63;
        float v = redv[(4 * tth) * 64 + tl]; int ix = redi[(4 * tth) * 64 + tl];
        #pragma unroll
        for (int ww = 1; ww < 4; ++ww) {
            const float ov = redv[(4 * tth + ww) * 64 + tl];
            const int   oi = redi[(4 * tth + ww) * 64 + tl];
            if (ov > v || (ov == v && oi < ix)) { v = ov; ix = oi; }
        }
        maxvS[t] = v;
        atomicAdd(&hist[ix], 1);
    }
    __syncthreads();

    // ---- fused quant epilogue: wave w handles tokens [16w, 16w+16) ----
    for (int i = 0; i < 16; ++i) {
        const int tl = 16 * w + i;
        const int tok = r0 + tl;
        const float4 x = ((const float4*)(X + (size_t)tok * DIM))[lane];
        const float4 r = ((const float4*)(R + (size_t)tok * DIM))[lane];

        float x2 = x.x * x.x + x.y * x.y + x.z * x.z + x.w * x.w;
        float n2 = r.x * r.x + r.y * r.y + r.z * r.z + r.w * r.w;
        #pragma unroll
        for (int d = 1; d < 64; d <<= 1) {
            x2 += __shfl_xor(x2, d);
            n2 += __shfl_xor(n2, d);
        }
        const float mv = maxvS[tl];
        const float d2 = fmaxf(fmaf(-2.f, mv, x2), 0.f);
        const float s = sqrtf(d2) / (sqrtf(n2) + EPSF);

        float4 o;
        o.x = fmaf(s, r.x, x.x);
        o.y = fmaf(s, r.y, x.y);
        o.z = fmaf(s, r.z, x.z);
        o.w = fmaf(s, r.w, x.w);
        ((float4*)(out + (size_t)tok * DIM))[lane] = o;
    }

    // ---- merged stats: last-arriving block computes perplexity+unique ----
    if (tid == 0) {
        __threadfence();
        amLast = (atomicAdd(&g_ctr, 1) == (int)gridDim.x - 1);
    }
    __syncthreads();
    if (amLast) {
        float s = 0.f; int u = 0;
        for (int b = tid; b < N_CODES; b += 512) {
            const int c = __hip_atomic_load(&hist[b], __ATOMIC_RELAXED,
                                            __HIP_MEMORY_SCOPE_AGENT);
            if (c > 0) ++u;
            const float p = (float)c * (1.f / (float)N_TOKENS);
            s += p * logf(p + EPSF);
        }
        #pragma unroll
        for (int d = 1; d < 64; d <<= 1) {
            s += __shfl_xor(s, d);
            u += __shfl_xor(u, d);
        }
        if (lane == 0) { redv[w] = s; redi[w] = u; }
        __syncthreads();
        if (tid == 0) {
            float st = 0.f; int ut = 0;
            #pragma unroll
            for (int i = 0; i < 8; ++i) { st += redv[i]; ut += redi[i]; }
            float* outs = out + (size_t)N_TOKENS * DIM;
            outs[0] = expf(-st);       // perplexity
            outs[1] = (float)ut;       // num_unique_indices
        }
    }
}

// ---------------------------------------------------------------------------
extern "C" void kernel_launch(void* const* d_in, const int* in_sizes, int n_in,
                              void* d_out, int out_size, void* d_ws, size_t ws_size,
                              hipStream_t stream) {
    const float* X = (const float*)d_in[0];  // input_data (32768,256)
    const float* R = (const float*)d_in[1];  // rand       (32768,256)
    const float* C = (const float*)d_in[2];  // codebooks  (8192,256)
    float* out = (float*)d_out;

    char* ws = (char*)d_ws;
    unsigned short* cbh = (unsigned short*)ws;             // bf16 codebooks
    float* cnorm = (float*)(ws + WS_CNORM_OFF);
    int*   hist  = (int*)(ws + WS_HIST_OFF);

    k_prep  <<<N_CODES / 4,    256, 0, stream>>>(C, cbh, cnorm, hist);
    k_argmin<<<N_TOKENS / 128, 512, 0, stream>>>(X, R, cbh, cnorm, out, hist);
}